// Round 5
// baseline (295.094 us; speedup 1.0000x reference)
//
#include <hip/hip_runtime.h>
#include <math.h>

#define NN 1024
#define HID 64
#define HID4 16             // HID/4 float4 chunks per feature row
#define HEADD 128
#define NODE_DIM 14
#define BATCH 32
#define CAP 64
#define ROWS (BATCH * NN)   // 32768
#define ZROW ROWS           // sentinel zero row (fits ushort)
#define GROW (ROWS + 16)    // rows allocated per g buffer
#define RPW 8               // rows per wave in layer kernels
#define GRID3 (ROWS / 32)   // k_layer3 grid (1024)

typedef float f4v __attribute__((ext_vector_type(4)));

// ---- swizzles (XCD-aware: blk%8 pins a batch's slab to one XCD L2) --------
__device__ __forceinline__ int swz4(int blk, int wv) {
    int x = blk & 7, q = blk >> 3;
    int batch = x + 8 * (q >> 8);
    return batch * NN + ((q & 255) << 2) + wv;
}
__device__ __forceinline__ int swz32(int blk, int wv) {
    int x = blk & 7, q = blk >> 3;          // q in [0,128)
    int batch = x + 8 * (q >> 5);
    return batch * NN + ((q & 31) << 5) + wv * RPW;
}

__device__ __forceinline__ float rl_f(float v, int k) {
    return __int_as_float(__builtin_amdgcn_readlane(__float_as_int(v), k));
}

// ---------------- K1: CSR build (ballot) + g1 = dinv*(x @ W1) ---------------
// csr stores GLOBAL row index, ZROW-PADDED to CAP so layer gathers need no
// masking; g buffers pre-scaled by dinv; row ZROW zeroed. Adjacency is a
// read-once 134 MB stream -> non-temporal loads.
__global__ __launch_bounds__(256) void k_build(const float* __restrict__ adj,
                                               const float* __restrict__ x,
                                               const float* __restrict__ W1,
                                               unsigned short* __restrict__ csr,
                                               int* __restrict__ nnz_g,
                                               float* __restrict__ dinv,
                                               float* __restrict__ g1,
                                               float* __restrict__ g2,
                                               float* __restrict__ g3,
                                               float* __restrict__ pooled,
                                               int* __restrict__ done) {
    __shared__ float sW1[NODE_DIM * HID];
    for (int i = threadIdx.x; i < NODE_DIM * HID; i += 256) sW1[i] = W1[i];
    if (blockIdx.x < 8) pooled[blockIdx.x * 256 + threadIdx.x] = 0.f;
    if (blockIdx.x == 8) {
        if (threadIdx.x < 64) {
            int t = threadIdx.x;
            g1[(size_t)ZROW * HID + t] = 0.f;
            g2[(size_t)ZROW * HID + t] = 0.f;
            g3[(size_t)ZROW * HID + t] = 0.f;
        }
        if (threadIdx.x == 64) *done = 0;
    }
    int wv = threadIdx.x >> 6, lane = threadIdx.x & 63;
    int row = swz4(blockIdx.x, wv);
    int brow = row & ~(NN - 1);             // batch base (global col offset)
    const f4v* rp = reinterpret_cast<const f4v*>(adj + (size_t)row * NN);
    unsigned long long lt = ((unsigned long long)1 << lane) - 1;
    int base = 0;
#pragma unroll
    for (int j = 0; j < 4; ++j) {
        f4v v = __builtin_nontemporal_load(rp + lane + 64 * j);
        float vv[4] = {v.x, v.y, v.z, v.w};
#pragma unroll
        for (int k = 0; k < 4; ++k) {
            unsigned long long mk = __ballot(vv[k] != 0.0f);
            if (mk) {                         // wave-uniform: skip empty masks (~53%)
                if (vv[k] != 0.0f) {
                    int pos = base + __popcll(mk & lt);
                    if (pos < CAP)
                        csr[row * CAP + pos] =
                            (unsigned short)(brow + (lane + 64 * j) * 4 + k);
                }
                base += __popcll(mk);
            }
        }
    }
    int nn = base < CAP ? base : CAP;
    if (lane >= nn)                           // pad tail with zero-row sentinel
        csr[row * CAP + lane] = (unsigned short)ZROW;
    float di = 1.0f / sqrtf((float)(base < 1 ? 1 : base));   // wave-uniform
    if (lane == 0) {
        nnz_g[row] = nn;
        dinv[row] = di;
    }
    __syncthreads();
    float acc = 0.f;
    const float* xr = x + (size_t)row * NODE_DIM;
#pragma unroll
    for (int d = 0; d < NODE_DIM; ++d) acc += xr[d] * sW1[d * HID + lane];
    g1[(size_t)row * HID + lane] = acc * di;     // pre-scaled
}

// Per-wave meta: ONE coalesced load each for nnz/dinv, readlane fan-out;
// idxv[r] = full (padded) neighbor list of row r, lane l holds neighbor l.
__device__ __forceinline__ int load_meta4(const int* __restrict__ nnz_g,
                                          const float* __restrict__ dinv,
                                          const unsigned short* __restrict__ csr,
                                          int row0, int lane,
                                          int idxv[RPW], float dr[RPW]) {
    int nv = nnz_g[row0 + (lane & 7)];
    float dvv = dinv[row0 + (lane & 7)];
    int nmax = 1;
#pragma unroll
    for (int r = 0; r < RPW; ++r) {
        int nr = __builtin_amdgcn_readlane(nv, r);
        nmax = nr > nmax ? nr : nmax;
        dr[r] = rl_f(dvv, r);
    }
#pragma unroll
    for (int r = 0; r < RPW; ++r)
        idxv[r] = (int)csr[(row0 + r) * CAP + lane];
    return (nmax + 3) >> 2;                   // macro-steps (4 neighbors each)
}

// float4 gather: lane = (group g = lane>>4, chunk s = lane&15). One load
// instruction fetches 4 neighbor rows (16 B/lane, 1 KB/instr). ZROW padding
// makes every access valid with +0.0 contribution.
__device__ __forceinline__ void spmm8v4(const float4* __restrict__ g4,
                                        int msteps, const int idxv[RPW],
                                        int g, unsigned s, float4 acc[RPW]) {
#pragma unroll
    for (int r = 0; r < RPW; ++r) acc[r] = make_float4(0.f, 0.f, 0.f, 0.f);
    for (int m = 0; m < msteps; ++m) {
        int b4 = (m << 2) + g;
        float4 v[RPW];
#pragma unroll
        for (int r = 0; r < RPW; ++r) {
            unsigned j = (unsigned)__builtin_amdgcn_ds_bpermute(b4 << 2, idxv[r]);
            v[r] = g4[j * (unsigned)HID4 + s];
        }
#pragma unroll
        for (int r = 0; r < RPW; ++r) {
            acc[r].x += v[r].x; acc[r].y += v[r].y;
            acc[r].z += v[r].z; acc[r].w += v[r].w;
        }
    }
}

// Cross-group reduce: groups 0..3 hold partial sums over neighbor subsets.
__device__ __forceinline__ void xreduce(float4 acc[RPW]) {
#pragma unroll
    for (int r = 0; r < RPW; ++r) {
        acc[r].x += __shfl_xor(acc[r].x, 16, 64);
        acc[r].y += __shfl_xor(acc[r].y, 16, 64);
        acc[r].z += __shfl_xor(acc[r].z, 16, 64);
        acc[r].w += __shfl_xor(acc[r].w, 16, 64);
        acc[r].x += __shfl_xor(acc[r].x, 32, 64);
        acc[r].y += __shfl_xor(acc[r].y, 32, 64);
        acc[r].z += __shfl_xor(acc[r].z, 32, 64);
        acc[r].w += __shfl_xor(acc[r].w, 32, 64);
    }
}

// ---------------- K2/K3: g_out = (dinv*relu(sum + b)) @ W  (pre-scaled) -----
__global__ __launch_bounds__(256, 4) void k_layer(const float* __restrict__ g_in,
                                                  const unsigned short* __restrict__ csr,
                                                  const int* __restrict__ nnz_g,
                                                  const float* __restrict__ dinv,
                                                  const float* __restrict__ bias,
                                                  const float* __restrict__ W,
                                                  float* __restrict__ g_out) {
    __shared__ float sW[HID * HID];
    {   // cooperative W load (16 KB), overlaps the gather phase
        const float4* Wv = reinterpret_cast<const float4*>(W);
        float4* sWv = reinterpret_cast<float4*>(sW);
        for (int i = threadIdx.x; i < HID * HID / 4; i += 256) sWv[i] = Wv[i];
    }
    int wv = threadIdx.x >> 6, lane = threadIdx.x & 63;
    int g = lane >> 4;
    unsigned s = (unsigned)(lane & 15);
    int row0 = swz32(blockIdx.x, wv);
    int idxv[RPW];
    float dr[RPW];
    int msteps = load_meta4(nnz_g, dinv, csr, row0, lane, idxv, dr);
    float4 acc[RPW];
    spmm8v4(reinterpret_cast<const float4*>(g_in), msteps, idxv, g, s, acc);
    xreduce(acc);
    float4 bb4 = reinterpret_cast<const float4*>(bias)[s];
    float h_[RPW][4];                          // dim d lives in lane d>>2, comp d&3
#pragma unroll
    for (int r = 0; r < RPW; ++r) {
        h_[r][0] = fmaxf(dr[r] * acc[r].x + bb4.x, 0.f) * dr[r];
        h_[r][1] = fmaxf(dr[r] * acc[r].y + bb4.y, 0.f) * dr[r];
        h_[r][2] = fmaxf(dr[r] * acc[r].z + bb4.z, 0.f) * dr[r];
        h_[r][3] = fmaxf(dr[r] * acc[r].w + bb4.w, 0.f) * dr[r];
    }
    __syncthreads();                           // sW ready
    float o[RPW];
#pragma unroll
    for (int r = 0; r < RPW; ++r) o[r] = 0.f;
#pragma unroll
    for (int d = 0; d < HID; ++d) {
        float w = sW[d * HID + lane];
#pragma unroll
        for (int r = 0; r < RPW; ++r)
            o[r] += rl_f(h_[r][d & 3], d >> 2) * w;
    }
#pragma unroll
    for (int r = 0; r < RPW; ++r)
        g_out[(size_t)(row0 + r) * HID + lane] = o[r];
}

// ------ K4: h3 = relu(dinv*sum + b3); pool; LAST block runs the head --------
// Completion handshake: pooled is written only via device-scope atomics (L2);
// one s_waitcnt vmcnt(0) orders this block's atomics before the done-counter
// increment (no __threadfence / cache writeback). Last block stages Wf1 in
// LDS and computes all 32 batch outputs with full 256-thread parallelism.
__global__ __launch_bounds__(256, 4) void k_layer3(const float* __restrict__ g_in,
                                                   const unsigned short* __restrict__ csr,
                                                   const int* __restrict__ nnz_g,
                                                   const float* __restrict__ dinv,
                                                   const float* __restrict__ bias,
                                                   float* __restrict__ pooled,
                                                   const float* __restrict__ Wf1,
                                                   const float* __restrict__ bf1,
                                                   const float* __restrict__ Wf2,
                                                   const float* __restrict__ bf2,
                                                   float* __restrict__ out,
                                                   int* __restrict__ done) {
    __shared__ float4 sred4[4][HID4];          // 1 KB
    __shared__ float sWf1[HID * HEADD];        // 32 KB (head phase only)
    __shared__ float sp[2][HID];
    __shared__ float spart[4];
    __shared__ int s_last;
    int wv = threadIdx.x >> 6, lane = threadIdx.x & 63;
    int g = lane >> 4;
    unsigned s = (unsigned)(lane & 15);
    int row0 = swz32(blockIdx.x, wv);
    int idxv[RPW];
    float dr[RPW];
    int msteps = load_meta4(nnz_g, dinv, csr, row0, lane, idxv, dr);
    float4 acc[RPW];
    spmm8v4(reinterpret_cast<const float4*>(g_in), msteps, idxv, g, s, acc);
    xreduce(acc);
    float4 bb4 = reinterpret_cast<const float4*>(bias)[s];
    float4 s4 = make_float4(0.f, 0.f, 0.f, 0.f);
#pragma unroll
    for (int r = 0; r < RPW; ++r) {            // unscaled h3 for pooling
        s4.x += fmaxf(dr[r] * acc[r].x + bb4.x, 0.f);
        s4.y += fmaxf(dr[r] * acc[r].y + bb4.y, 0.f);
        s4.z += fmaxf(dr[r] * acc[r].z + bb4.z, 0.f);
        s4.w += fmaxf(dr[r] * acc[r].w + bb4.w, 0.f);
    }
    if (lane < 16) sred4[wv][lane] = s4;       // lanes 0..15 hold full copies
    __syncthreads();
    if (wv == 0) {
        if (lane < 16) {
            float4 t;
            t.x = sred4[0][lane].x + sred4[1][lane].x + sred4[2][lane].x + sred4[3][lane].x;
            t.y = sred4[0][lane].y + sred4[1][lane].y + sred4[2][lane].y + sred4[3][lane].y;
            t.z = sred4[0][lane].z + sred4[1][lane].z + sred4[2][lane].z + sred4[3][lane].z;
            t.w = sred4[0][lane].w + sred4[1][lane].w + sred4[2][lane].w + sred4[3][lane].w;
            float* pb = &pooled[(row0 >> 10) * HID + 4 * lane];
            atomicAdd(pb + 0, t.x);
            atomicAdd(pb + 1, t.y);
            atomicAdd(pb + 2, t.z);
            atomicAdd(pb + 3, t.w);
        }
        if (lane == 0) {                       // same wave as the atomics above
            asm volatile("s_waitcnt vmcnt(0)" ::: "memory");  // atomics complete
            int c = __hip_atomic_fetch_add(done, 1, __ATOMIC_RELAXED,
                                           __HIP_MEMORY_SCOPE_AGENT);
            s_last = (c == GRID3 - 1);
        }
    }
    __syncthreads();
    if (!s_last) return;

    // ---------------- head (last block only) -------------------------------
    {   // stage Wf1 (32 KB) into LDS
        const float4* Wv = reinterpret_cast<const float4*>(Wf1);
        float4* sWv = reinterpret_cast<float4*>(sWf1);
        for (int i = threadIdx.x; i < HID * HEADD / 4; i += 256) sWv[i] = Wv[i];
    }
    int sub = threadIdx.x >> 7;                // 0/1: two batches per pass
    int t = threadIdx.x & 127;
    float wb1 = bf1[t], wf2 = Wf2[t];
    __syncthreads();                           // sWf1 ready
    for (int it = 0; it < BATCH / 2; ++it) {
        int b = it * 2 + sub;
        if (t < HID)                           // L1-bypassing coherent read
            sp[sub][t] = __hip_atomic_load(&pooled[b * HID + t],
                                           __ATOMIC_RELAXED,
                                           __HIP_MEMORY_SCOPE_AGENT) * (1.0f / NN);
        __syncthreads();
        float acc2 = wb1;
#pragma unroll 8
        for (int d = 0; d < HID; ++d) acc2 += sp[sub][d] * sWf1[d * HEADD + t];
        float v = fmaxf(acc2, 0.f) * wf2;
#pragma unroll
        for (int off = 32; off > 0; off >>= 1) v += __shfl_down(v, off, 64);
        if ((threadIdx.x & 63) == 0) spart[threadIdx.x >> 6] = v;
        __syncthreads();
        if (t == 0)                            // tid 0 and tid 128
            out[b] = spart[sub * 2] + spart[sub * 2 + 1] + bf2[0];
        __syncthreads();
    }
}

extern "C" void kernel_launch(void* const* d_in, const int* in_sizes, int n_in,
                              void* d_out, int out_size, void* d_ws, size_t ws_size,
                              hipStream_t stream) {
    const float* x   = (const float*)d_in[0];
    const float* adj = (const float*)d_in[1];
    const float* W1  = (const float*)d_in[2];
    const float* b1  = (const float*)d_in[3];
    const float* W2  = (const float*)d_in[4];
    const float* b2  = (const float*)d_in[5];
    const float* W3  = (const float*)d_in[6];
    const float* b3  = (const float*)d_in[7];
    const float* Wf1 = (const float*)d_in[8];
    const float* bf1 = (const float*)d_in[9];
    const float* Wf2 = (const float*)d_in[10];
    const float* bf2 = (const float*)d_in[11];
    float* out = (float*)d_out;

    // ws carve: csr(ushort) 4MB | nnz 128KB | dinv 128KB | pooled 16KB | done |
    //           g1,g2,g3 each (ROWS+16) rows (row ZROW zeroed per launch)
    char* ws = (char*)d_ws;
    size_t off = 0;
    unsigned short* csr = (unsigned short*)(ws + off); off += (size_t)ROWS * CAP * 2;
    int*   nnz_g  = (int*)(ws + off);   off += (size_t)ROWS * 4;
    float* dinv   = (float*)(ws + off); off += (size_t)ROWS * 4;
    float* pooled = (float*)(ws + off); off += 4096 * 4;
    int*   done   = (int*)(ws + off);   off += 256;        // keep alignment
    float* g1     = (float*)(ws + off); off += (size_t)GROW * HID * 4;
    float* g2     = (float*)(ws + off); off += (size_t)GROW * HID * 4;
    float* g3     = (float*)(ws + off);

    k_build <<<ROWS / 4, 256, 0, stream>>>(adj, x, W1, csr, nnz_g, dinv,
                                           g1, g2, g3, pooled, done);
    k_layer <<<ROWS / 32, 256, 0, stream>>>(g1, csr, nnz_g, dinv, b1, W2, g2);
    k_layer <<<ROWS / 32, 256, 0, stream>>>(g2, csr, nnz_g, dinv, b2, W3, g3);
    k_layer3<<<GRID3, 256, 0, stream>>>(g3, csr, nnz_g, dinv, b3, pooled,
                                        Wf1, bf1, Wf2, bf2, out, done);
}

// Round 6
// 270.152 us; speedup vs baseline: 1.0923x; 1.0923x over previous
//
#include <hip/hip_runtime.h>
#include <math.h>

#define NN 1024
#define HID 64
#define HID4 16             // HID/4 float4 chunks per feature row
#define HEADD 128
#define NODE_DIM 14
#define BATCH 32
#define CAP 64
#define ROWS (BATCH * NN)   // 32768
#define ZROW ROWS           // sentinel zero row (fits ushort)
#define GROW (ROWS + 16)    // rows allocated per g buffer
#define RPW 8               // rows per wave in layer kernels

// ---- swizzles (XCD-aware: blk%8 pins a batch's slab to one XCD L2) --------
// k_build: 2048 blocks, 16 rows each (4 waves x 4 rows sequential).
__device__ __forceinline__ int swz16(int blk, int wv) {
    int x = blk & 7, q = blk >> 3;          // q in [0,256)
    int batch = x + 8 * (q >> 6);
    return batch * NN + ((q & 63) << 4) + wv * 4;
}
__device__ __forceinline__ int swz32(int blk, int wv) {
    int x = blk & 7, q = blk >> 3;          // q in [0,128)
    int batch = x + 8 * (q >> 5);
    return batch * NN + ((q & 31) << 5) + wv * RPW;
}

__device__ __forceinline__ float rl_f(float v, int k) {
    return __int_as_float(__builtin_amdgcn_readlane(__float_as_int(v), k));
}

// ---------------- K1: CSR build (ballot) + g1 = dinv*(x @ W1) ---------------
// csr stores GLOBAL row index, ZROW-PADDED to CAP so layer gathers need no
// masking; g buffers pre-scaled by dinv; row ZROW zeroed.
// 4 rows per wave sequentially -> 2048 blocks (was 8192): same DRAM traffic,
// 4x fewer block dispatches.
__global__ __launch_bounds__(256) void k_build(const float* __restrict__ adj,
                                               const float* __restrict__ x,
                                               const float* __restrict__ W1,
                                               unsigned short* __restrict__ csr,
                                               int* __restrict__ nnz_g,
                                               float* __restrict__ dinv,
                                               float* __restrict__ g1,
                                               float* __restrict__ g2,
                                               float* __restrict__ g3,
                                               float* __restrict__ pooled) {
    __shared__ float sW1[NODE_DIM * HID];
    for (int i = threadIdx.x; i < NODE_DIM * HID; i += 256) sW1[i] = W1[i];
    if (blockIdx.x < 8) pooled[blockIdx.x * 256 + threadIdx.x] = 0.f;
    if (blockIdx.x == 8 && threadIdx.x < 64) {
        int t = threadIdx.x;
        g1[(size_t)ZROW * HID + t] = 0.f;
        g2[(size_t)ZROW * HID + t] = 0.f;
        g3[(size_t)ZROW * HID + t] = 0.f;
    }
    int wv = threadIdx.x >> 6, lane = threadIdx.x & 63;
    int row0 = swz16(blockIdx.x, wv);
    int brow = row0 & ~(NN - 1);            // batch base (global col offset)
    unsigned long long lt = ((unsigned long long)1 << lane) - 1;
    __syncthreads();                        // sW1 ready (once, before row loop)
    for (int rr = 0; rr < 4; ++rr) {
        int row = row0 + rr;
        const float4* rp = reinterpret_cast<const float4*>(adj + (size_t)row * NN);
        int base = 0;
#pragma unroll
        for (int j = 0; j < 4; ++j) {
            float4 v = rp[lane + 64 * j];
            float vv[4] = {v.x, v.y, v.z, v.w};
#pragma unroll
            for (int k = 0; k < 4; ++k) {
                unsigned long long mk = __ballot(vv[k] != 0.0f);
                if (mk) {                     // wave-uniform: skip empty masks (~53%)
                    if (vv[k] != 0.0f) {
                        int pos = base + __popcll(mk & lt);
                        if (pos < CAP)
                            csr[row * CAP + pos] =
                                (unsigned short)(brow + (lane + 64 * j) * 4 + k);
                    }
                    base += __popcll(mk);
                }
            }
        }
        int nn = base < CAP ? base : CAP;
        if (lane >= nn)                       // pad tail with zero-row sentinel
            csr[row * CAP + lane] = (unsigned short)ZROW;
        float di = 1.0f / sqrtf((float)(base < 1 ? 1 : base));  // wave-uniform
        if (lane == 0) {
            nnz_g[row] = nn;
            dinv[row] = di;
        }
        float acc = 0.f;
        const float* xr = x + (size_t)row * NODE_DIM;
#pragma unroll
        for (int d = 0; d < NODE_DIM; ++d) acc += xr[d] * sW1[d * HID + lane];
        g1[(size_t)row * HID + lane] = acc * di;   // pre-scaled
    }
}

// Per-wave meta: ONE coalesced load each for nnz/dinv, readlane fan-out;
// idxv[r] = full (padded) neighbor list of row r, lane l holds neighbor l.
__device__ __forceinline__ int load_meta4(const int* __restrict__ nnz_g,
                                          const float* __restrict__ dinv,
                                          const unsigned short* __restrict__ csr,
                                          int row0, int lane,
                                          int idxv[RPW], float dr[RPW]) {
    int nv = nnz_g[row0 + (lane & 7)];
    float dvv = dinv[row0 + (lane & 7)];
    int nmax = 1;
#pragma unroll
    for (int r = 0; r < RPW; ++r) {
        int nr = __builtin_amdgcn_readlane(nv, r);
        nmax = nr > nmax ? nr : nmax;
        dr[r] = rl_f(dvv, r);
    }
#pragma unroll
    for (int r = 0; r < RPW; ++r)
        idxv[r] = (int)csr[(row0 + r) * CAP + lane];
    return (nmax + 3) >> 2;                   // macro-steps (4 neighbors each)
}

// float4 gather: lane = (group g = lane>>4, chunk s = lane&15). One load
// instruction fetches 4 neighbor rows (16 B/lane, 1 KB/instr). ZROW padding
// makes every access valid with +0.0 contribution.
__device__ __forceinline__ void spmm8v4(const float4* __restrict__ g4,
                                        int msteps, const int idxv[RPW],
                                        int g, unsigned s, float4 acc[RPW]) {
#pragma unroll
    for (int r = 0; r < RPW; ++r) acc[r] = make_float4(0.f, 0.f, 0.f, 0.f);
    for (int m = 0; m < msteps; ++m) {
        int b4 = (m << 2) + g;
        float4 v[RPW];
#pragma unroll
        for (int r = 0; r < RPW; ++r) {
            unsigned j = (unsigned)__builtin_amdgcn_ds_bpermute(b4 << 2, idxv[r]);
            v[r] = g4[j * (unsigned)HID4 + s];
        }
#pragma unroll
        for (int r = 0; r < RPW; ++r) {
            acc[r].x += v[r].x; acc[r].y += v[r].y;
            acc[r].z += v[r].z; acc[r].w += v[r].w;
        }
    }
}

// Cross-group reduce: groups 0..3 hold partial sums over neighbor subsets.
__device__ __forceinline__ void xreduce(float4 acc[RPW]) {
#pragma unroll
    for (int r = 0; r < RPW; ++r) {
        acc[r].x += __shfl_xor(acc[r].x, 16, 64);
        acc[r].y += __shfl_xor(acc[r].y, 16, 64);
        acc[r].z += __shfl_xor(acc[r].z, 16, 64);
        acc[r].w += __shfl_xor(acc[r].w, 16, 64);
        acc[r].x += __shfl_xor(acc[r].x, 32, 64);
        acc[r].y += __shfl_xor(acc[r].y, 32, 64);
        acc[r].z += __shfl_xor(acc[r].z, 32, 64);
        acc[r].w += __shfl_xor(acc[r].w, 32, 64);
    }
}

// ---------------- K2/K3: g_out = (dinv*relu(sum + b)) @ W  (pre-scaled) -----
__global__ __launch_bounds__(256, 4) void k_layer(const float* __restrict__ g_in,
                                                  const unsigned short* __restrict__ csr,
                                                  const int* __restrict__ nnz_g,
                                                  const float* __restrict__ dinv,
                                                  const float* __restrict__ bias,
                                                  const float* __restrict__ W,
                                                  float* __restrict__ g_out) {
    __shared__ float sW[HID * HID];
    {   // cooperative W load (16 KB), overlaps the gather phase
        const float4* Wv = reinterpret_cast<const float4*>(W);
        float4* sWv = reinterpret_cast<float4*>(sW);
        for (int i = threadIdx.x; i < HID * HID / 4; i += 256) sWv[i] = Wv[i];
    }
    int wv = threadIdx.x >> 6, lane = threadIdx.x & 63;
    int g = lane >> 4;
    unsigned s = (unsigned)(lane & 15);
    int row0 = swz32(blockIdx.x, wv);
    int idxv[RPW];
    float dr[RPW];
    int msteps = load_meta4(nnz_g, dinv, csr, row0, lane, idxv, dr);
    float4 acc[RPW];
    spmm8v4(reinterpret_cast<const float4*>(g_in), msteps, idxv, g, s, acc);
    xreduce(acc);
    float4 bb4 = reinterpret_cast<const float4*>(bias)[s];
    float h_[RPW][4];                          // dim d lives in lane d>>2, comp d&3
#pragma unroll
    for (int r = 0; r < RPW; ++r) {
        h_[r][0] = fmaxf(dr[r] * acc[r].x + bb4.x, 0.f) * dr[r];
        h_[r][1] = fmaxf(dr[r] * acc[r].y + bb4.y, 0.f) * dr[r];
        h_[r][2] = fmaxf(dr[r] * acc[r].z + bb4.z, 0.f) * dr[r];
        h_[r][3] = fmaxf(dr[r] * acc[r].w + bb4.w, 0.f) * dr[r];
    }
    __syncthreads();                           // sW ready
    float o[RPW];
#pragma unroll
    for (int r = 0; r < RPW; ++r) o[r] = 0.f;
#pragma unroll
    for (int d = 0; d < HID; ++d) {
        float w = sW[d * HID + lane];
#pragma unroll
        for (int r = 0; r < RPW; ++r)
            o[r] += rl_f(h_[r][d & 3], d >> 2) * w;
    }
#pragma unroll
    for (int r = 0; r < RPW; ++r)
        g_out[(size_t)(row0 + r) * HID + lane] = o[r];
}

// ---------------- K4: h3 = relu(dinv*sum + b3); pool ------------------------
__global__ __launch_bounds__(256, 4) void k_layer3(const float* __restrict__ g_in,
                                                   const unsigned short* __restrict__ csr,
                                                   const int* __restrict__ nnz_g,
                                                   const float* __restrict__ dinv,
                                                   const float* __restrict__ bias,
                                                   float* __restrict__ pooled) {
    __shared__ float4 sred4[4][HID4];
    int wv = threadIdx.x >> 6, lane = threadIdx.x & 63;
    int g = lane >> 4;
    unsigned s = (unsigned)(lane & 15);
    int row0 = swz32(blockIdx.x, wv);
    int idxv[RPW];
    float dr[RPW];
    int msteps = load_meta4(nnz_g, dinv, csr, row0, lane, idxv, dr);
    float4 acc[RPW];
    spmm8v4(reinterpret_cast<const float4*>(g_in), msteps, idxv, g, s, acc);
    xreduce(acc);
    float4 bb4 = reinterpret_cast<const float4*>(bias)[s];
    float4 s4 = make_float4(0.f, 0.f, 0.f, 0.f);
#pragma unroll
    for (int r = 0; r < RPW; ++r) {            // unscaled h3 for pooling
        s4.x += fmaxf(dr[r] * acc[r].x + bb4.x, 0.f);
        s4.y += fmaxf(dr[r] * acc[r].y + bb4.y, 0.f);
        s4.z += fmaxf(dr[r] * acc[r].z + bb4.z, 0.f);
        s4.w += fmaxf(dr[r] * acc[r].w + bb4.w, 0.f);
    }
    if (lane < 16) sred4[wv][lane] = s4;       // lanes 0..15 hold full copies
    __syncthreads();
    if (wv == 0 && lane < 16) {
        float4 t;
        t.x = sred4[0][lane].x + sred4[1][lane].x + sred4[2][lane].x + sred4[3][lane].x;
        t.y = sred4[0][lane].y + sred4[1][lane].y + sred4[2][lane].y + sred4[3][lane].y;
        t.z = sred4[0][lane].z + sred4[1][lane].z + sred4[2][lane].z + sred4[3][lane].z;
        t.w = sred4[0][lane].w + sred4[1][lane].w + sred4[2][lane].w + sred4[3][lane].w;
        float* pb = &pooled[(row0 >> 10) * HID + 4 * lane];
        atomicAdd(pb + 0, t.x);
        atomicAdd(pb + 1, t.y);
        atomicAdd(pb + 2, t.z);
        atomicAdd(pb + 3, t.w);
    }
}

// ---------------- K5: head ---------------------------------------------------
__global__ __launch_bounds__(128) void k_head(const float* __restrict__ pooled_sum,
                                              const float* __restrict__ Wf1,
                                              const float* __restrict__ bf1,
                                              const float* __restrict__ Wf2,
                                              const float* __restrict__ bf2,
                                              float* __restrict__ out) {
    int b = blockIdx.x, t = threadIdx.x;
    __shared__ float p[HID];
    __shared__ float hid[HEADD];
    if (t < HID) p[t] = pooled_sum[b * HID + t] * (1.0f / NN);
    __syncthreads();
    float acc = bf1[t];
    for (int d = 0; d < HID; ++d) acc += p[d] * Wf1[d * HEADD + t];
    hid[t] = fmaxf(acc, 0.f);
    __syncthreads();
    if (t < 64) {
        float v = hid[t] * Wf2[t] + hid[t + 64] * Wf2[t + 64];
#pragma unroll
        for (int off = 32; off > 0; off >>= 1) v += __shfl_down(v, off, 64);
        if (t == 0) out[b] = v + bf2[0];
    }
}

extern "C" void kernel_launch(void* const* d_in, const int* in_sizes, int n_in,
                              void* d_out, int out_size, void* d_ws, size_t ws_size,
                              hipStream_t stream) {
    const float* x   = (const float*)d_in[0];
    const float* adj = (const float*)d_in[1];
    const float* W1  = (const float*)d_in[2];
    const float* b1  = (const float*)d_in[3];
    const float* W2  = (const float*)d_in[4];
    const float* b2  = (const float*)d_in[5];
    const float* W3  = (const float*)d_in[6];
    const float* b3  = (const float*)d_in[7];
    const float* Wf1 = (const float*)d_in[8];
    const float* bf1 = (const float*)d_in[9];
    const float* Wf2 = (const float*)d_in[10];
    const float* bf2 = (const float*)d_in[11];
    float* out = (float*)d_out;

    // ws carve: csr(ushort) 4MB | nnz 128KB | dinv 128KB | pooled 16KB |
    //           g1,g2,g3 each (ROWS+16) rows (row ZROW zeroed per launch)
    char* ws = (char*)d_ws;
    size_t off = 0;
    unsigned short* csr = (unsigned short*)(ws + off); off += (size_t)ROWS * CAP * 2;
    int*   nnz_g  = (int*)(ws + off);   off += (size_t)ROWS * 4;
    float* dinv   = (float*)(ws + off); off += (size_t)ROWS * 4;
    float* pooled = (float*)(ws + off); off += 4096 * 4;
    float* g1     = (float*)(ws + off); off += (size_t)GROW * HID * 4;
    float* g2     = (float*)(ws + off); off += (size_t)GROW * HID * 4;
    float* g3     = (float*)(ws + off);

    k_build <<<ROWS / 16, 256, 0, stream>>>(adj, x, W1, csr, nnz_g, dinv,
                                            g1, g2, g3, pooled);
    k_layer <<<ROWS / 32, 256, 0, stream>>>(g1, csr, nnz_g, dinv, b1, W2, g2);
    k_layer <<<ROWS / 32, 256, 0, stream>>>(g2, csr, nnz_g, dinv, b2, W3, g3);
    k_layer3<<<ROWS / 32, 256, 0, stream>>>(g3, csr, nnz_g, dinv, b3, pooled);
    k_head  <<<BATCH, 128, 0, stream>>>(pooled, Wf1, bf1, Wf2, bf2, out);
}